// Round 9
// baseline (47.953 us; speedup 1.0000x reference)
//
#include <hip/hip_runtime.h>
#include <hip/hip_bf16.h>

// Locally-connected 2D conv via MFMA (bf16 inputs, fp32 accumulate).
// x:(8,32,64,64)  weights:(64,64,32,32,3,3)  bias:(32)  out:(8,32,64,64)
// out[b,o,i,j] = bias[o] + sum_k xpatch[b,k] * W[loc][o][k],  k=c*9+a*3+bb,
//   xpatch[b,k] = x[b, c, i+bb-1, j+a-1]   (a=col offset, bb=row offset)
//
// R8: COALESCED weight fetch. 4096 WGs x 128 thr, one location per WG,
// wave = o-tile. The W slab for a location (32 o x 288 k = 36.9 KB) is
// contiguous: 18 wave-instructions of lane-consecutive float4 -> LDS
// (o-row padded to 292 floats), then per-lane ds_read_b128 pairs pick the
// verified B-frag order. x rows -> LDS at b-stride 292 (banks 4*bm: spread;
// R7's stride-288 8-way conflict fixed). ONE barrier total; 36 global
// loads in flight until it. No obuf: MFMA D lanes store out directly.
// Frag/D layouts identical to R5/R6 (numerically verified).

#define NB 8
#define NC 32
#define NO 32
#define NH 64
#define NW 64
#define KK 288
#define WS4 73                          // padded o-row stride in float4
#define XBS 292                         // padded per-b stride in floats

typedef __attribute__((ext_vector_type(8))) short s16x8;
typedef __attribute__((ext_vector_type(4))) float f32x4;

union Frag { unsigned short s[8]; uint4 q; s16x8 v; };

__device__ __forceinline__ unsigned short f2bf(float f) {
  __hip_bfloat16 h = __float2bfloat16(f);   // HW cvt (RNE) on gfx950
  return *reinterpret_cast<unsigned short*>(&h);
}

__global__ __launch_bounds__(128, 2) void lc2d_kernel(
    const float* __restrict__ x, const float* __restrict__ w,
    const float* __restrict__ bias, float* __restrict__ out) {
  const int bid = blockIdx.x;                    // 0..4095
  const int g = (bid & 7) * 512 + (bid >> 3);    // XCD-bijective cluster
  const int i = g >> 6;
  const int j0 = g & 63;
  const int t = threadIdx.x;
  const int lane = t & 63;
  const int ot = t >> 6;                         // wave = o-tile 0/1
  const int m16 = lane & 15;
  const int kg = lane >> 4;                      // k-group 0..3
  const int bm = m16 & 7;                        // A-row (b); rows 8-15 dup
  const int o_ = ot * 16 + m16;

  __shared__ float4 ws4[NO * WS4];               // 37376 B (w slab, padded)
  __shared__ float xnat[NB * XBS];               //  9344 B (x patch, padded)

  // ---- 1. x-stage loads (3 cols: j0-1..j0+1), 18 dwords/thread ----
  // data idx e = b*288 + (c*3+bb)*3 + a  ->  x[b, c, i+bb-1, j0+a-1]
  float xv_[18];
#pragma unroll
  for (int it = 0; it < 18; ++it) {
    int e = t + it * 128;                        // < 2304
    int row = e / 3;                             // b*96 + c*3 + bb
    int a = e - row * 3;
    int b_ = row / 96;
    int rem = row - b_ * 96;
    int c = rem / 3;
    int bb = rem - c * 3;
    int y = i + bb - 1;
    int xc = j0 + a - 1;
    float v = 0.f;
    if ((unsigned)y < 64u && (unsigned)xc < 64u)
      v = x[((b_ * NC + c) * NH + y) * NW + xc];
    xv_[it] = v;
  }

  // ---- 2. weight slab, COALESCED: lane-consecutive float4 ----
  const float4* wb = reinterpret_cast<const float4*>(w + (size_t)g * NO * KK);
  float4 wv_[18];
#pragma unroll
  for (int it = 0; it < 18; ++it) wv_[it] = wb[t + it * 128];

  const float bia = bias[o_];

  // ---- 3. publish LDS (compiler inserts per-load vmcnt waits) ----
#pragma unroll
  for (int it = 0; it < 18; ++it) {
    int e = t + it * 128;
    int b_ = e / 288;
    xnat[e + 4 * b_] = xv_[it];                  // padded: b*292 + rest
  }
#pragma unroll
  for (int it = 0; it < 18; ++it) {
    int f = t + it * 128;                        // slab float4 index
    int o = f / 72;
    int r = f - o * 72;
    ws4[o * WS4 + r] = wv_[it];
  }
  asm volatile("s_waitcnt lgkmcnt(0)\n\ts_barrier" ::: "memory");

  // ---- 4. A-frag gather: lane row bm, k = ks*32 + kg*8 + e ----
  uint4 afr[9];
#pragma unroll
  for (int ks = 0; ks < 9; ++ks) {
    Frag f;
#pragma unroll
    for (int e = 0; e < 8; ++e) {
      int k = ks * 32 + kg * 8 + e;
      int c = k / 9;
      int rem = k - c * 9;
      int a = rem / 3;                           // col offset (W axis)
      int bb = rem - a * 3;                      // row offset (H axis)
      f.s[e] = f2bf(xnat[bm * XBS + (c * 3 + bb) * 3 + a]);
    }
    afr[ks] = f.q;
  }

  // ---- 5. B-frags from LDS slab + 9 MFMA ----
  f32x4 acc = {0.f, 0.f, 0.f, 0.f};
#pragma unroll
  for (int ks = 0; ks < 9; ++ks) {
    float4 lo = ws4[o_ * WS4 + ks * 8 + kg * 2];
    float4 hi = ws4[o_ * WS4 + ks * 8 + kg * 2 + 1];
    Frag fb;
    fb.s[0] = f2bf(lo.x); fb.s[1] = f2bf(lo.y);
    fb.s[2] = f2bf(lo.z); fb.s[3] = f2bf(lo.w);
    fb.s[4] = f2bf(hi.x); fb.s[5] = f2bf(hi.y);
    fb.s[6] = f2bf(hi.z); fb.s[7] = f2bf(hi.w);
    Frag fa; fa.q = afr[ks];
    acc = __builtin_amdgcn_mfma_f32_16x16x32_bf16(fa.v, fb.v, acc, 0, 0, 0);
  }

  // ---- 6. D: row = kg*4 + r = b, col = m16; store direct ----
  if (kg < 2) {
#pragma unroll
    for (int r = 0; r < 4; ++r) {
      int b_ = kg * 4 + r;
      out[((size_t)(b_ * NO + o_) * NH + i) * NW + j0] = acc[r] + bia;
    }
  }
}

extern "C" void kernel_launch(void* const* d_in, const int* in_sizes, int n_in,
                              void* d_out, int out_size, void* d_ws, size_t ws_size,
                              hipStream_t stream) {
  const float* x    = (const float*)d_in[0];
  const float* w    = (const float*)d_in[1];
  const float* bias = (const float*)d_in[2];
  float* out = (float*)d_out;
  lc2d_kernel<<<dim3(NH * NW), dim3(128), 0, stream>>>(x, w, bias, out);
}

// Round 10
// 46.620 us; speedup vs baseline: 1.0286x; 1.0286x over previous
//
#include <hip/hip_runtime.h>
#include <hip/hip_bf16.h>

// Locally-connected 2D conv via MFMA (bf16 inputs, fp32 accumulate).
// x:(8,32,64,64)  weights:(64,64,32,32,3,3)  bias:(32)  out:(8,32,64,64)
// out[b,o,i,j] = bias[o] + sum_k xpatch[b,k] * W[loc][o][k],  k=c*9+a*3+bb,
//   xpatch[b,k] = x[b, c, i+bb-1, j+a-1]   (a=col offset, bb=row offset)
//
// R9 = R6-structure + full persistence + R4-style weight rotation.
// 1024 WGs x 256 thr = exactly 4 WGs/CU co-resident (16 waves), ONE round:
// no WG turnover. Each WG owns 4 locations (same i, j0..j0+3); wave wv
// runs two (loc, o-tile) phases: (la=wv>>1, ot=wv&1) then (lb=la+2, ot).
// Phase-A weights (18 dwordx4/lane) issued in the prologue; phase-B's 18
// issued inside phase-A's MFMA loop into the just-freed registers -> the
// weight stream never idles (R6's ~20% duty gap at WG turnover/compute).
// x staged once for all 4 locs (padded b-stride 578 -> gather banks 2*bm,
// conflict-free); 2 lgkm-only barriers total, vmcnt never drained by them.
// Frag/D layouts identical to R5/R6 (numerically verified).

#define NB 8
#define NC 32
#define NO 32
#define NH 64
#define NW 64
#define KK 288
#define LOCS 4
#define XCOLS 6                        // j0-1 .. j0+4
#define BSTRIDE 578                    // 96 rows * 6 cols + 2 pad
#define XNAT_SZ (NB * BSTRIDE)         // 4624 floats = 18496 B

typedef __attribute__((ext_vector_type(8))) short s16x8;
typedef __attribute__((ext_vector_type(4))) float f32x4;

union Frag { unsigned short s[8]; uint4 q; s16x8 v; };

__device__ __forceinline__ unsigned short f2bf(float f) {
  __hip_bfloat16 h = __float2bfloat16(f);   // HW cvt (RNE) on gfx950
  return *reinterpret_cast<unsigned short*>(&h);
}

__global__ __launch_bounds__(256, 4) void lc2d_kernel(
    const float* __restrict__ x, const float* __restrict__ w,
    const float* __restrict__ bias, float* __restrict__ out) {
  const int bid = blockIdx.x;                    // 0..1023
  const int g = (bid & 7) * 128 + (bid >> 3);    // XCD-bijective cluster
  const int loc0 = g * LOCS;
  const int i = loc0 >> 6;                       // 4 | 64 -> same i per WG
  const int j0 = loc0 & 63;
  const int t = threadIdx.x;
  const int lane = t & 63;
  const int wv = t >> 6;                         // wave 0..3
  const int m16 = lane & 15;
  const int kg = lane >> 4;                      // k-group 0..3
  const int bm = m16 & 7;                        // A-row (b); rows 8-15 dup
  const int ot = wv & 1;                         // o-tile for both phases
  const int la = wv >> 1;                        // phase-A loc (0/1)
  const int lb = la + 2;                         // phase-B loc (2/3)
  const int o_ = ot * 16 + m16;

  __shared__ float xnat[XNAT_SZ];                // 18496 B
  __shared__ float obuf[LOCS][NB][NO];           //  4096 B

  // ---- 1. x-stage loads into regs (issued FIRST: oldest in vmcnt) ----
  // e = b*576 + (c*3+bb)*6 + cc  ->  x[b, c, i+bb-1, j0+cc-1]
  float sv[18];
#pragma unroll
  for (int it = 0; it < 18; ++it) {
    int e = t + it * 256;                        // < 4608
    int b_ = e / 576;
    int r = e - b_ * 576;
    int row = r / XCOLS;                         // c*3 + bb
    int cc = r - row * XCOLS;
    int c = row / 3;
    int bb = row - c * 3;
    int y = i + bb - 1;
    int xc = j0 + cc - 1;
    float v = 0.f;
    if ((unsigned)y < 64u && (unsigned)xc < 64u)
      v = x[((b_ * NC + c) * NH + y) * NW + xc];
    sv[it] = v;
  }
  asm volatile("" ::: "memory");  // keep weight-load issue after stage loads

  // ---- 2. phase-A weight loads: 18 dwordx4, in flight to MFMA-A ----
  float4 wf[18];
  {
    const float* wp =
        w + ((size_t)(loc0 + la) * NO + o_) * KK + kg * 8;
#pragma unroll
    for (int ks = 0; ks < 9; ++ks) {
      wf[2 * ks]     = *(const float4*)(wp + ks * 32);
      wf[2 * ks + 1] = *(const float4*)(wp + ks * 32 + 4);
    }
  }

  // ---- 3. publish xnat (ds_writes drain only the x loads: vmcnt(18)) ----
#pragma unroll
  for (int it = 0; it < 18; ++it) {
    int e = t + it * 256;
    int b_ = e / 576;
    int r = e - b_ * 576;
    xnat[b_ * BSTRIDE + r] = sv[it];
  }
  asm volatile("s_waitcnt lgkmcnt(0)\n\ts_barrier" ::: "memory");

  // ---- A-frag gather helper: lane row bm, k = ks*32 + kg*8 + e ----
  auto gather = [&](int l, uint4 afr[9]) {
#pragma unroll
    for (int ks = 0; ks < 9; ++ks) {
      Frag f;
#pragma unroll
      for (int e = 0; e < 8; ++e) {
        int k = ks * 32 + kg * 8 + e;
        int c = k / 9;
        int rem = k - c * 9;
        int a = rem / 3;                         // col offset (W axis)
        int bb = rem - a * 3;                    // row offset (H axis)
        f.s[e] = f2bf(xnat[bm * BSTRIDE + (c * 3 + bb) * XCOLS + l + a]);
      }
      afr[ks] = f.q;
    }
  };

  // ---- 4. phase A: MFMA + rotate phase-B weights into freed regs ----
  uint4 afr[9];
  gather(la, afr);
  {
    const float* wpB =
        w + ((size_t)(loc0 + lb) * NO + o_) * KK + kg * 8;
    f32x4 acc = {0.f, 0.f, 0.f, 0.f};
#pragma unroll
    for (int ks = 0; ks < 9; ++ks) {
      float4 lo = wf[2 * ks], hi = wf[2 * ks + 1];
      Frag fb;
      fb.s[0] = f2bf(lo.x); fb.s[1] = f2bf(lo.y);
      fb.s[2] = f2bf(lo.z); fb.s[3] = f2bf(lo.w);
      fb.s[4] = f2bf(hi.x); fb.s[5] = f2bf(hi.y);
      fb.s[6] = f2bf(hi.z); fb.s[7] = f2bf(hi.w);
      Frag fa; fa.q = afr[ks];
      acc = __builtin_amdgcn_mfma_f32_16x16x32_bf16(fa.v, fb.v, acc, 0, 0, 0);
      wf[2 * ks]     = *(const float4*)(wpB + ks * 32);   // rotate B in
      wf[2 * ks + 1] = *(const float4*)(wpB + ks * 32 + 4);
    }
    if (kg < 2) {
#pragma unroll
      for (int r = 0; r < 4; ++r)
        obuf[la][kg * 4 + r][o_] = acc[r];
    }
  }

  // ---- 5. phase B: gather + MFMA (no rotation) ----
  gather(lb, afr);
  {
    f32x4 acc = {0.f, 0.f, 0.f, 0.f};
#pragma unroll
    for (int ks = 0; ks < 9; ++ks) {
      float4 lo = wf[2 * ks], hi = wf[2 * ks + 1];
      Frag fb;
      fb.s[0] = f2bf(lo.x); fb.s[1] = f2bf(lo.y);
      fb.s[2] = f2bf(lo.z); fb.s[3] = f2bf(lo.w);
      fb.s[4] = f2bf(hi.x); fb.s[5] = f2bf(hi.y);
      fb.s[6] = f2bf(hi.z); fb.s[7] = f2bf(hi.w);
      Frag fa; fa.q = afr[ks];
      acc = __builtin_amdgcn_mfma_f32_16x16x32_bf16(fa.v, fb.v, acc, 0, 0, 0);
    }
    if (kg < 2) {
#pragma unroll
      for (int r = 0; r < 4; ++r)
        obuf[lb][kg * 4 + r][o_] = acc[r];
    }
  }
  asm volatile("s_waitcnt lgkmcnt(0)\n\ts_barrier" ::: "memory");

  // ---- 6. final store: thread t = (b,o); out[b,o,i,j0..j0+3] ----
  {
    const int b_ = t >> 5;
    const int oo = t & 31;
    const float bia = bias[oo];
    float4 r4;
    r4.x = obuf[0][b_][oo] + bia;
    r4.y = obuf[1][b_][oo] + bia;
    r4.z = obuf[2][b_][oo] + bia;
    r4.w = obuf[3][b_][oo] + bia;
    *reinterpret_cast<float4*>(
        &out[((size_t)(b_ * NO + oo) * NH + i) * NW + j0]) = r4;
  }
}

extern "C" void kernel_launch(void* const* d_in, const int* in_sizes, int n_in,
                              void* d_out, int out_size, void* d_ws, size_t ws_size,
                              hipStream_t stream) {
  const float* x    = (const float*)d_in[0];
  const float* w    = (const float*)d_in[1];
  const float* bias = (const float*)d_in[2];
  float* out = (float*)d_out;
  lc2d_kernel<<<dim3(NH * NW / LOCS), dim3(256), 0, stream>>>(x, w, bias, out);
}

// Round 11
// 33.689 us; speedup vs baseline: 1.4234x; 1.3838x over previous
//
#include <hip/hip_runtime.h>
#include <hip/hip_bf16.h>

// Locally-connected 2D conv via MFMA (bf16 inputs, fp32 accumulate).
// x:(8,32,64,64)  weights:(64,64,32,32,3,3)  bias:(32)  out:(8,32,64,64)
// out[b,o,i,j] = bias[o] + sum_k xpatch[b,k] * W[loc][o][k],  k=c*9+a*3+bb,
//   xpatch[b,k] = x[b, c, i+bb-1, j+a-1]   (a=col offset, bb=row offset)
//
// R10 = R6 restored (best: 33.8 us). One wave per (loc, o-tile) phase.
// 2048 WGs x 256thr, LOCS=2 per WG, 4 WGs/CU (16 waves). Per wave: issue
// 12 x-stage + 18 weight dwordx4 up front (weights stay in flight through
// stage+frag-build; in-order vmcnt), then 9 MFMA consuming weights as they
// land (HW v_cvt bf16). 3 raw lgkm-only barriers per WG; vmcnt never
// drained by them.
//
// Roofline rationale (R7/R8/R9 post-mortems): the weight stream is
// read-once (151 MB); sustaining it needs in-flight bytes x waves/CU,
// which is register-file-capped at ~16 waves x 336 B/lane = the observed
// ~4.9-5 TB/s. All three attempts to exceed it (512-thr WGs, coalesced
// LDS slab, persistent rotation) regressed via occupancy loss or spill.

#define NB 8
#define NC 32
#define NO 32
#define NH 64
#define NW 64
#define KK 288
#define LOCS 2
#define XCOLS 4                        // j0-1 .. j0+2
#define NROWS (NB * NC * 3)            // 768
#define XNAT_SZ (NROWS * XCOLS)        // 3072 floats
#define NSLOT (LOCS * 9 * 32)          // 576 A-frag slots (16 B each)

typedef __attribute__((ext_vector_type(8))) short s16x8;
typedef __attribute__((ext_vector_type(4))) float f32x4;

union Frag { unsigned short s[8]; uint4 q; s16x8 v; };

__device__ __forceinline__ unsigned short f2bf(float f) {
  __hip_bfloat16 h = __float2bfloat16(f);   // HW cvt (RNE) on gfx950
  return *reinterpret_cast<unsigned short*>(&h);
}

__global__ __launch_bounds__(256, 4) void lc2d_kernel(
    const float* __restrict__ x, const float* __restrict__ w,
    const float* __restrict__ bias, float* __restrict__ out) {
  const int bid = blockIdx.x;                    // 0..2047
  const int g = (bid & 7) * 256 + (bid >> 3);    // XCD-bijective cluster
  const int loc0 = g * LOCS;
  const int i = loc0 >> 6;                       // 2 | 64 -> same i per WG
  const int j0 = loc0 & 63;
  const int t = threadIdx.x;
  const int lane = t & 63;
  const int wv = t >> 6;                         // wave 0..3
  const int m16 = lane & 15;
  const int kg = lane >> 4;                      // k-group 0..3
  const int l = wv >> 1;                         // this wave's loc (0/1)
  const int ot = wv & 1;                         // this wave's o-tile (0/1)

  __shared__ float xnat[XNAT_SZ];                // 12288 B
  __shared__ uint4 xtb[NSLOT];                   //  9216 B  (bf16 A-frags)
  __shared__ float obuf[LOCS][NB][NO];           //  2048 B

  // ---- 1. x-stage loads into regs (issued first; oldest in vmcnt) ----
  float sv[12];
#pragma unroll
  for (int it = 0; it < 12; ++it) {
    int e = t + it * 256;
    int row = e >> 2;                  // (b*32+c)*3 + yy
    int cc = e & 3;
    int bc = row / 3;
    int yy = row - bc * 3;
    int y = i + yy - 1;
    int xc = j0 + cc - 1;
    float v = 0.f;
    if ((unsigned)y < 64u && (unsigned)xc < 64u)
      v = x[(bc * NH + y) * NW + xc];
    sv[it] = v;
  }

  // ---- 2. weight loads: 18 dwordx4, in flight until the MFMA loop ----
  // lane (m16 = o-in-tile, kg = k-chunk): W[o][ks*32 + kg*8 + 0..7]
  float4 wf[18];
  {
    const float* wp =
        w + ((size_t)(loc0 + l) * NO + ot * 16 + m16) * KK + kg * 8;
#pragma unroll
    for (int ks = 0; ks < 9; ++ks) {
      wf[2 * ks]     = *(const float4*)(wp + ks * 32);
      wf[2 * ks + 1] = *(const float4*)(wp + ks * 32 + 4);
    }
  }

  // ---- 3. publish xnat (ds_writes wait only the stage loads: vmcnt(18)) ----
#pragma unroll
  for (int it = 0; it < 12; ++it) xnat[t + it * 256] = sv[it];
  asm volatile("s_waitcnt lgkmcnt(0)\n\ts_barrier" ::: "memory");

  // ---- 4. build bf16 A-frags: slot (l2, ks, kg*8+b) = 8 bf16 of row b ----
  for (int sid = t; sid < NSLOT; sid += 256) {
    int l2 = sid / 288;                // 9*32 slots per loc
    int r = sid - l2 * 288;
    int ks = r >> 5;
    int idx = r & 31;
    int bkg = idx >> 3;
    int bm = idx & 7;
    Frag f;
#pragma unroll
    for (int e = 0; e < 8; ++e) {
      int k = ks * 32 + bkg * 8 + e;
      int c = k / 9;
      int rem = k - c * 9;
      int a = rem / 3;                 // col offset (W axis)
      int bb = rem - a * 3;            // row offset (H axis)
      f.s[e] = f2bf(xnat[((bm * NC + c) * 3 + bb) * XCOLS + l2 + a]);
    }
    xtb[sid] = f.q;
  }
  asm volatile("s_waitcnt lgkmcnt(0)\n\ts_barrier" ::: "memory");

  // ---- 5. A-frags (rows 8-15 duplicate 0-7; D rows 8-15 discarded) ----
  uint4 afr[9];
#pragma unroll
  for (int ks = 0; ks < 9; ++ks)
    afr[ks] = xtb[(l * 9 + ks) * 32 + kg * 8 + (m16 & 7)];

  // ---- 6. cvt weights as they land + 9 MFMA ----
  f32x4 acc = {0.f, 0.f, 0.f, 0.f};
#pragma unroll
  for (int ks = 0; ks < 9; ++ks) {
    float4 lo = wf[2 * ks], hi = wf[2 * ks + 1];
    Frag fb;
    fb.s[0] = f2bf(lo.x); fb.s[1] = f2bf(lo.y);
    fb.s[2] = f2bf(lo.z); fb.s[3] = f2bf(lo.w);
    fb.s[4] = f2bf(hi.x); fb.s[5] = f2bf(hi.y);
    fb.s[6] = f2bf(hi.z); fb.s[7] = f2bf(hi.w);
    Frag fa; fa.q = afr[ks];
    acc = __builtin_amdgcn_mfma_f32_16x16x32_bf16(fa.v, fb.v, acc, 0, 0, 0);
  }

  // ---- D: row = kg*4 + r = b, col = m16 = o-in-tile ----
  if (kg < 2) {
#pragma unroll
    for (int r = 0; r < 4; ++r)
      obuf[l][kg * 4 + r][ot * 16 + m16] = acc[r];
  }
  asm volatile("s_waitcnt lgkmcnt(0)\n\ts_barrier" ::: "memory");

  // ---- 7. final store: thread t = (b,o); out[b,o,i,j0..j0+1] ----
  {
    const int b_ = t >> 5;
    const int o_ = t & 31;
    const float bia = bias[o_];
    float2 r2;
    r2.x = obuf[0][b_][o_] + bia;
    r2.y = obuf[1][b_][o_] + bia;
    *reinterpret_cast<float2*>(
        &out[((size_t)(b_ * NO + o_) * NH + i) * NW + j0]) = r2;
  }
}

extern "C" void kernel_launch(void* const* d_in, const int* in_sizes, int n_in,
                              void* d_out, int out_size, void* d_ws, size_t ws_size,
                              hipStream_t stream) {
  const float* x    = (const float*)d_in[0];
  const float* w    = (const float*)d_in[1];
  const float* bias = (const float*)d_in[2];
  float* out = (float*)d_out;
  lc2d_kernel<<<dim3(NH * NW / LOCS), dim3(256), 0, stream>>>(x, w, bias, out);
}